// Round 5
// baseline (119.209 us; speedup 1.0000x reference)
//
#include <hip/hip_runtime.h>
#include <hip/hip_bf16.h>
#include <hip/hip_fp8.h>
#include <math.h>

typedef float floatx4 __attribute__((ext_vector_type(4)));
typedef long long i64;
typedef long long i64x2 __attribute__((ext_vector_type(2)));

#define N_ROWS 4096
#define DIM 512
#define LAM 0.5f
#define NT2 32                       // 256-row block-tiles per dim (8192/256)
#define NTILES2 (NT2 * (NT2 + 1) / 2) // 528 triangular tiles
#define GRID 256                     // persistent: 1 block/CU (128 KB LDS)

#define GLOBAL_AS(p) ((const __attribute__((address_space(1))) void*)(p))
#define LDS_AS(p) ((__attribute__((address_space(3))) void*)(p))

__device__ __forceinline__ unsigned int pack4_fp8(float a, float b, float c, float d) {
    unsigned int u0 = __hip_cvt_float_to_fp8(a, __HIP_SATFINITE, __HIP_E4M3);
    unsigned int u1 = __hip_cvt_float_to_fp8(b, __HIP_SATFINITE, __HIP_E4M3);
    unsigned int u2 = __hip_cvt_float_to_fp8(c, __HIP_SATFINITE, __HIP_E4M3);
    unsigned int u3 = __hip_cvt_float_to_fp8(d, __HIP_SATFINITE, __HIP_E4M3);
    return u0 | (u1 << 8) | (u2 << 16) | (u3 << 24);
}

// One wave per row: L2-normalize 512 fp32 -> fp8 e4m3, stored K-PERMUTED and
// BANK-SWIZZLED. 16-B chunk ch = kt*4+q (kt: 64-k group, q: MFMA quad) holds
// k = kt*64 + {q*8..q*8+7 (lo 8B), 32+q*8..+7 (hi 8B)}; chunk is stored at
// physical position p = ch ^ (row & 7). The XOR only touches the low 3 bits,
// so each 128-B (8-chunk) group is closed under the permutation -> the GEMM
// may stage any BK multiple of 128 as a plain physical byte copy.
__global__ __launch_bounds__(256) void normalize_kernel(
    const float* __restrict__ ei, const float* __restrict__ ej,
    unsigned char* __restrict__ Z, float* __restrict__ out) {
    if (blockIdx.x == 0 && threadIdx.x == 0) out[0] = 0.0f;
    const int w = threadIdx.x >> 6, lane = threadIdx.x & 63;
    const int row = blockIdx.x * 4 + w;                     // [0, 8192)
    const float* __restrict__ src = (row < N_ROWS)
        ? (ei + (size_t)row * DIM)
        : (ej + (size_t)(row - N_ROWS) * DIM);
    const float4* src4 = (const float4*)src;
    float4 v0 = src4[lane];
    float4 v1 = src4[lane + 64];
    float s = v0.x*v0.x + v0.y*v0.y + v0.z*v0.z + v0.w*v0.w
            + v1.x*v1.x + v1.y*v1.y + v1.z*v1.z + v1.w*v1.w;
    #pragma unroll
    for (int off = 32; off; off >>= 1) s += __shfl_xor(s, off);
    const float r = rsqrtf(s);

    __shared__ __align__(16) unsigned char buf[4][512];     // k-linear fp8 rows
    ((unsigned int*)buf[w])[lane]      = pack4_fp8(v0.x*r, v0.y*r, v0.z*r, v0.w*r);
    ((unsigned int*)buf[w])[lane + 64] = pack4_fp8(v1.x*r, v1.y*r, v1.z*r, v1.w*r);
    __syncthreads();

    // full-wave permuted store: lane = kt*8 + q*2 + h, 8 B each
    const int kt = lane >> 3, q = (lane >> 1) & 3, h = lane & 1;
    i64 val = *(const i64*)(buf[w] + kt * 64 + h * 32 + q * 8);
    const int p = (kt * 4 + q) ^ (row & 7);                 // bank swizzle
    *(i64*)(Z + (size_t)row * DIM + p * 16 + h * 8) = val;
}

// Fused S = Z.Z^T (fp8 16x16x32 MFMA) + loss reduction.
// NEW this round (rounds 2-4: three micro-theories flat; corrected stage
// model says 128^2/2-block structure runs ~42% pipe-fed with per-stage fixed
// costs (LDS port 192KB rd + 64KB wr per CU-stage, lgkm chains, 2x
// vmcnt+barrier joins) dominating the rest):
//   STRUCTURAL: 256x256 tile, ONE 8-wave block/CU (512 thr, 128 KB LDS,
//   2 waves/SIMD). Per CU-stage: staged bytes unchanged (64 KB) but FLOP
//   doubles -> half the stage-events, half the staged-bytes/FLOP, double
//   MFMA per barrier interval (5043 cyc pipe/SIMD-stage vs 2520).
//   Waves: 4 row-groups (wr) x 2 col-groups (wc); wave tile 64x128.
//   setprio REMOVED (m190: hurts lockstep symmetric-wave GEMM - ours).
//   Pipeline: BK=128 dbuf, continuous vmcnt(0)->barrier->issue per stage
//   (wait-before-barrier REQUIRED: staging is cooperative across waves).
//   528 tiles = 2x256 + 16 extras (bid%16==0 takes a 3rd tile).
__global__ __launch_bounds__(512, 2) void simloss_kernel(
    const unsigned char* __restrict__ Z, float* __restrict__ out) {
    const int tid = threadIdx.x;
    const int w = tid >> 6, lane = tid & 63;
    const int q = lane >> 4, m16 = lane & 15;
    const int wr = w & 3, wc = w >> 2;      // 4x2 wave grid, wave tile 64x128

    __shared__ __align__(16) unsigned char As[2][256 * 128];  // 32 KB per buf
    __shared__ __align__(16) unsigned char Bs[2][256 * 128];
    __shared__ float red[8];

    const int ldsOff = w * 1024;
    const int fragSwz = m16 & 7;
    // staging: instr l (0..3): rows l*64 + w*8 + (lane>>3), byte (lane&7)*16
    // LDS slot = l*8192 + w*1024 + lane*16 (lane-linear physical byte copy)
    const int stRow = w * 8 + (lane >> 3);
    const int stCol = (lane & 7) * 16;

    const int bid = blockIdx.x;
    const int nMine = 2 + ((bid & 15) == 0);   // 528 = 2*256 + 16 extras

    auto decode = [](int id, int& bm, int& bn) {
        int m = (int)((2*NT2 + 1 - sqrtf((float)((2*NT2+1)*(2*NT2+1)) - 8.0f * (float)id)) * 0.5f);
        if (m < 0) m = 0; if (m > NT2-1) m = NT2-1;
        while ((m + 1) * NT2 - ((m + 1) * m) / 2 <= id) ++m;
        while (m * NT2 - (m * (m - 1)) / 2 > id) --m;
        bm = m;
        bn = m + (id - (m * NT2 - (m * (m - 1)) / 2));
    };
    auto tileIdx = [bid](int mt) {
        return (mt < 2) ? (bid + mt * GRID) : (2 * GRID + (bid >> 4));
    };

    int bm, bn; decode(tileIdx(0), bm, bn);
    const unsigned char* stA = Z + (size_t)(bm * 256 + stRow) * DIM + stCol;
    const unsigned char* stB = Z + (size_t)(bn * 256 + stRow) * DIM + stCol;

    float negsum = 0.0f, possum = 0.0f;

    // one BK=128 stage: A-panel 256x128B (4 instr) + B-panel 256x128B (4 instr)
    #define ISSUE(par, pA, pB, kOff)                                             \
        _Pragma("unroll")                                                        \
        for (int l = 0; l < 4; ++l) {                                            \
            __builtin_amdgcn_global_load_lds(GLOBAL_AS((pA) + (size_t)l * 64 * DIM + (kOff)), \
                                             LDS_AS(&As[par][l * 8192 + ldsOff]), 16, 0, 0);  \
            __builtin_amdgcn_global_load_lds(GLOBAL_AS((pB) + (size_t)l * 64 * DIM + (kOff)), \
                                             LDS_AS(&Bs[par][l * 8192 + ldsOff]), 16, 0, 0);  \
        }

    // prologue: tile 0, stage 0 -> buf 0
    ISSUE(0, stA, stB, 0)

    for (int mt = 0; mt < nMine; ++mt) {
        const bool hasNext = (mt + 1 < nMine);
        int nbm = 0, nbn = 0;
        const unsigned char *nA = stA, *nB = stB;
        if (hasNext) {
            decode(tileIdx(mt + 1), nbm, nbn);
            nA = Z + (size_t)(nbm * 256 + stRow) * DIM + stCol;
            nB = Z + (size_t)(nbn * 256 + stRow) * DIM + stCol;
        }

        floatx4 acc[4][8] = {};   // 4 row-frags x 8 col-frags (64x128 out)

        #pragma unroll
        for (int s = 0; s < 4; ++s) {
            const int par = (mt * 4 + s) & 1;   // continuous buffer parity
            // my stage-s loads done BEFORE the barrier (cooperative staging:
            // other waves read LDS written by my loads)
            asm volatile("s_waitcnt vmcnt(0)" ::: "memory");
            __builtin_amdgcn_sched_barrier(0);
            __builtin_amdgcn_s_barrier();       // publishes stage-s LDS; also
                                                // proves buf[par^1] readers done
            if (s < 3)        { ISSUE(par ^ 1, stA, stB, (s + 1) * 128) }
            else if (hasNext) { ISSUE(par ^ 1, nA, nB, 0) }

            const unsigned char* fraA = &As[par][(wr * 64 + m16) * 128];
            const unsigned char* fraB = &Bs[par][(wc * 128 + m16) * 128];
            #pragma unroll
            for (int g = 0; g < 2; ++g) {       // two K=64 groups
                const int cOff = ((g * 4 + q) ^ fragSwz) << 4;
                i64x2 af[4], bf[8];
                #pragma unroll
                for (int i = 0; i < 4; ++i) af[i] = *(const i64x2*)(fraA + i * 16 * 128 + cOff);
                #pragma unroll
                for (int j = 0; j < 8; ++j) bf[j] = *(const i64x2*)(fraB + j * 16 * 128 + cOff);
                // x-pass (32 independent), then y-pass (dep distance 32)
                #pragma unroll
                for (int i = 0; i < 4; ++i)
                    #pragma unroll
                    for (int j = 0; j < 8; ++j)
                        acc[i][j] = __builtin_amdgcn_mfma_f32_16x16x32_fp8_fp8(af[i].x, bf[j].x, acc[i][j], 0, 0, 0);
                #pragma unroll
                for (int i = 0; i < 4; ++i)
                    #pragma unroll
                    for (int j = 0; j < 8; ++j)
                        acc[i][j] = __builtin_amdgcn_mfma_f32_16x16x32_fp8_fp8(af[i].y, bf[j].y, acc[i][j], 0, 0, 0);
            }
        }

        // --- epilogue (no barriers; next tile's loads in flight) ---
        // C/D: global row = bm*256 + wr*64 + i*16 + q*4 + r,
        //      global col = bn*256 + wc*128 + j*16 + m16
        const int tm = bm * 4 + wr;             // 64-unit row id
        const int rowBase = bm * 256 + wr * 64 + q * 4;
        const int colBase = bn * 256 + wc * 128 + m16;
        #pragma unroll
        for (int j = 0; j < 8; ++j) {
            const int tn = bn * 4 + wc * 2 + (j >> 2);   // 64-unit col id
            const float wgt = (tn < tm) ? 0.0f : ((tn == tm) ? 1.0f : 2.0f);
            const bool hasPos = (tn == tm + 64);
            if (wgt == 0.0f) continue;          // wave-uniform-per-j skip
            const int cg = colBase + j * 16;
            float p = 1.0f;
            #pragma unroll
            for (int i = 0; i < 4; ++i) {
                const int rg0 = rowBase + i * 16;
                #pragma unroll
                for (int r = 0; r < 4; ++r) {
                    const float sv = acc[i][j][r];
                    float e = __expf(sv - LAM);
                    if (rg0 + r == cg) e = 0.0f;          // main diagonal
                    p *= (1.0f + e);
                    if (hasPos && cg == rg0 + r + N_ROWS) // positive pair
                        possum += log1pf(expf(-sv + LAM));
                }
            }
            negsum += __logf(p) * wgt;
        }

        bm = nbm; bn = nbn; stA = nA; stB = nB;
    }

    // --- block reduction: one atomic per block ---
    #pragma unroll
    for (int off = 32; off; off >>= 1) {
        negsum += __shfl_xor(negsum, off);
        possum += __shfl_xor(possum, off);
    }
    const float part = negsum * (1.0f / (12.0f * (float)N_ROWS))
                     + possum * (1.0f / (float)N_ROWS);
    if (lane == 0) red[w] = part;
    __syncthreads();
    if (tid == 0) {
        float t = 0.0f;
        #pragma unroll
        for (int i = 0; i < 8; ++i) t += red[i];
        atomicAdd(out, t);
    }
    #undef ISSUE
}

extern "C" void kernel_launch(void* const* d_in, const int* in_sizes, int n_in,
                              void* d_out, int out_size, void* d_ws, size_t ws_size,
                              hipStream_t stream) {
    const float* ei = (const float*)d_in[0];
    const float* ej = (const float*)d_in[1];
    float* out = (float*)d_out;
    unsigned char* Z = (unsigned char*)d_ws;  // 8192*512 fp8 = 4 MB scratch

    normalize_kernel<<<2048, 256, 0, stream>>>(ei, ej, Z, out);
    simloss_kernel<<<GRID, 512, 0, stream>>>(Z, out);
}

// Round 6
// 100.883 us; speedup vs baseline: 1.1817x; 1.1817x over previous
//
#include <hip/hip_runtime.h>
#include <hip/hip_bf16.h>
#include <hip/hip_fp8.h>
#include <math.h>

typedef float floatx4 __attribute__((ext_vector_type(4)));
typedef long long i64;
typedef long long i64x2 __attribute__((ext_vector_type(2)));

#define N_ROWS 4096
#define DIM 512
#define LAM 0.5f
#define NT 64                      // 128-row block-tiles per dim (8192/128)
#define NTILES (NT * (NT + 1) / 2) // 2080 triangular tiles
#define GRID 512                   // persistent: 2 blocks/CU (64 KB LDS each)

#define GLOBAL_AS(p) ((const __attribute__((address_space(1))) void*)(p))
#define LDS_AS(p) ((__attribute__((address_space(3))) void*)(p))

__device__ __forceinline__ unsigned int pack4_fp8(float a, float b, float c, float d) {
    unsigned int u0 = __hip_cvt_float_to_fp8(a, __HIP_SATFINITE, __HIP_E4M3);
    unsigned int u1 = __hip_cvt_float_to_fp8(b, __HIP_SATFINITE, __HIP_E4M3);
    unsigned int u2 = __hip_cvt_float_to_fp8(c, __HIP_SATFINITE, __HIP_E4M3);
    unsigned int u3 = __hip_cvt_float_to_fp8(d, __HIP_SATFINITE, __HIP_E4M3);
    return u0 | (u1 << 8) | (u2 << 16) | (u3 << 24);
}

// One wave per row: L2-normalize 512 fp32 -> fp8 e4m3, stored K-PERMUTED and
// BANK-SWIZZLED. 16-B chunk ch = kt*4+q (kt: 64-k group, q: MFMA quad) holds
// k = kt*64 + {q*8..q*8+7 (lo 8B), 32+q*8..+7 (hi 8B)}; chunk is stored at
// physical position p = ch ^ (row & 7). The XOR only touches the low 3 bits,
// so each 128-B (8-chunk) group is closed under the permutation -> the GEMM
// may stage any BK multiple of 128 as a plain physical byte copy.
__global__ __launch_bounds__(256) void normalize_kernel(
    const float* __restrict__ ei, const float* __restrict__ ej,
    unsigned char* __restrict__ Z, float* __restrict__ out) {
    if (blockIdx.x == 0 && threadIdx.x == 0) out[0] = 0.0f;
    const int w = threadIdx.x >> 6, lane = threadIdx.x & 63;
    const int row = blockIdx.x * 4 + w;                     // [0, 8192)
    const float* __restrict__ src = (row < N_ROWS)
        ? (ei + (size_t)row * DIM)
        : (ej + (size_t)(row - N_ROWS) * DIM);
    const float4* src4 = (const float4*)src;
    float4 v0 = src4[lane];
    float4 v1 = src4[lane + 64];
    float s = v0.x*v0.x + v0.y*v0.y + v0.z*v0.z + v0.w*v0.w
            + v1.x*v1.x + v1.y*v1.y + v1.z*v1.z + v1.w*v1.w;
    #pragma unroll
    for (int off = 32; off; off >>= 1) s += __shfl_xor(s, off);
    const float r = rsqrtf(s);

    __shared__ __align__(16) unsigned char buf[4][512];     // k-linear fp8 rows
    ((unsigned int*)buf[w])[lane]      = pack4_fp8(v0.x*r, v0.y*r, v0.z*r, v0.w*r);
    ((unsigned int*)buf[w])[lane + 64] = pack4_fp8(v1.x*r, v1.y*r, v1.z*r, v1.w*r);
    __syncthreads();

    // full-wave permuted store: lane = kt*8 + q*2 + h, 8 B each
    const int kt = lane >> 3, q = (lane >> 1) & 3, h = lane & 1;
    i64 val = *(const i64*)(buf[w] + kt * 64 + h * 32 + q * 8);
    const int p = (kt * 4 + q) ^ (row & 7);                 // bank swizzle
    *(i64*)(Z + (size_t)row * DIM + p * 16 + h * 8) = val;
}

// Fused S = Z.Z^T (fp8 16x16x32 MFMA) + loss reduction.
// Round-5 post-mortem: 256^2 single-block/CU REGRESSED (simloss 41 -> 58.7
// us, MfmaUtil 21.7%): merging all 8 waves of a CU into ONE barrier domain
// means nothing issues while the block sits in vmcnt/barrier - R2's 2
// independent blocks were what hid the per-stage serial phase. REVERTED to
// the 128^2 / BK=128-dbuf / 64 KB / 2-blocks-per-CU structure (best: 100.8).
// NEW this round: 8 waves per block (512 thr), wave sub-tile 32x64 (was 4
// waves of 64x64) -> 4 waves/SIMD from 2 INDEPENDENT barrier domains. When
// one block stalls (vmcnt wait, barrier join, lgkm head, epilogue), the
// other block now has 2 waves/SIMD of MFMA backlog per SIMD to cover it.
// VGPR drops (acc = 8 floatx4), so 4 waves/SIMD is legal at launch_bounds
// (512,4). Pipeline unchanged: continuous single-barrier, vmcnt(0) own-loads
// wait before the publishing barrier (staging is cooperative), issue next
// stage right after.
__global__ __launch_bounds__(512, 4) void simloss_kernel(
    const unsigned char* __restrict__ Z, float* __restrict__ out) {
    const int tid = threadIdx.x;
    const int w = tid >> 6, lane = tid & 63;
    const int q = lane >> 4, m16 = lane & 15;
    const int wr = w & 3, wc = w >> 2;      // 4x2 wave grid, wave tile 32x64

    __shared__ __align__(16) unsigned char As[2][128 * 128];  // 16 KB per buf
    __shared__ __align__(16) unsigned char Bs[2][128 * 128];
    __shared__ float red[8];

    const int fragSwz = m16 & 7;
    // staging: wave w, instr l (0..1): rows w*16 + l*8 + (lane>>3),
    // byte (lane&7)*16; LDS slot = w*2048 + l*1024 + lane*16 (lane-linear)
    const int stRow = w * 16 + (lane >> 3);
    const int stCol = (lane & 7) * 16;
    const int ldsOff = w * 2048;

    const int bid = blockIdx.x;
    // 2080 = 512*4 + 32 extras, spread every 16th bid
    const int nMine = 4 + ((bid & 15) == 0);

    auto decode = [](int id, int& bm, int& bn) {
        int m = (int)((2*NT + 1 - sqrtf((float)((2*NT+1)*(2*NT+1)) - 8.0f * (float)id)) * 0.5f);
        if (m < 0) m = 0; if (m > NT-1) m = NT-1;
        while ((m + 1) * NT - ((m + 1) * m) / 2 <= id) ++m;
        while (m * NT - (m * (m - 1)) / 2 > id) --m;
        bm = m;
        bn = m + (id - (m * NT - (m * (m - 1)) / 2));
    };
    auto tileIdx = [bid](int mt) {
        return (mt < 4) ? (bid + mt * GRID) : (4 * GRID + (bid >> 4));
    };

    int bm, bn; decode(tileIdx(0), bm, bn);
    const unsigned char* stA = Z + (size_t)(bm * 128 + stRow) * DIM + stCol;
    const unsigned char* stB = Z + (size_t)(bn * 128 + stRow) * DIM + stCol;

    float negsum = 0.0f, possum = 0.0f;

    // one BK=128 stage: A 128x128B (2 instr/wave) + B 128x128B (2 instr/wave)
    #define ISSUE(par, pA, pB, kOff)                                             \
        _Pragma("unroll")                                                        \
        for (int l = 0; l < 2; ++l) {                                            \
            __builtin_amdgcn_global_load_lds(GLOBAL_AS((pA) + (size_t)l * 8 * DIM + (kOff)), \
                                             LDS_AS(&As[par][ldsOff + l * 1024]), 16, 0, 0); \
            __builtin_amdgcn_global_load_lds(GLOBAL_AS((pB) + (size_t)l * 8 * DIM + (kOff)), \
                                             LDS_AS(&Bs[par][ldsOff + l * 1024]), 16, 0, 0); \
        }

    // prologue: tile 0, stage 0 -> buf 0
    ISSUE(0, stA, stB, 0)

    for (int mt = 0; mt < nMine; ++mt) {
        const bool hasNext = (mt + 1 < nMine);
        int nbm = 0, nbn = 0;
        const unsigned char *nA = stA, *nB = stB;
        if (hasNext) {
            decode(tileIdx(mt + 1), nbm, nbn);
            nA = Z + (size_t)(nbm * 128 + stRow) * DIM + stCol;
            nB = Z + (size_t)(nbn * 128 + stRow) * DIM + stCol;
        }

        floatx4 acc[2][4] = {};   // 2 row-frags x 4 col-frags (32x64 out)

        #pragma unroll
        for (int s = 0; s < 4; ++s) {
            const int par = (mt * 4 + s) & 1;   // continuous buffer parity
            // my stage-s loads done BEFORE the barrier (cooperative staging)
            asm volatile("s_waitcnt vmcnt(0)" ::: "memory");
            __builtin_amdgcn_sched_barrier(0);
            __builtin_amdgcn_s_barrier();       // publishes stage-s LDS; also
                                                // proves buf[par^1] readers done
            if (s < 3)        { ISSUE(par ^ 1, stA, stB, (s + 1) * 128) }
            else if (hasNext) { ISSUE(par ^ 1, nA, nB, 0) }

            const unsigned char* fraA = &As[par][(wr * 32 + m16) * 128];
            const unsigned char* fraB = &Bs[par][(wc * 64 + m16) * 128];
            #pragma unroll
            for (int g = 0; g < 2; ++g) {       // two K=64 groups
                const int cOff = ((g * 4 + q) ^ fragSwz) << 4;
                i64x2 af[2], bf[4];
                #pragma unroll
                for (int i = 0; i < 2; ++i) af[i] = *(const i64x2*)(fraA + i * 16 * 128 + cOff);
                #pragma unroll
                for (int j = 0; j < 4; ++j) bf[j] = *(const i64x2*)(fraB + j * 16 * 128 + cOff);
                __builtin_amdgcn_s_setprio(1);
                // x-pass (8 independent), then y-pass (dep distance 8)
                #pragma unroll
                for (int i = 0; i < 2; ++i)
                    #pragma unroll
                    for (int j = 0; j < 4; ++j)
                        acc[i][j] = __builtin_amdgcn_mfma_f32_16x16x32_fp8_fp8(af[i].x, bf[j].x, acc[i][j], 0, 0, 0);
                #pragma unroll
                for (int i = 0; i < 2; ++i)
                    #pragma unroll
                    for (int j = 0; j < 4; ++j)
                        acc[i][j] = __builtin_amdgcn_mfma_f32_16x16x32_fp8_fp8(af[i].y, bf[j].y, acc[i][j], 0, 0, 0);
                __builtin_amdgcn_s_setprio(0);
            }
        }

        // --- epilogue (no barriers; next tile's loads in flight) ---
        // C/D: global row = bm*128 + wr*32 + i*16 + q*4 + r,
        //      global col = bn*128 + wc*64 + j*16 + m16
        const int tm = bm * 2 + (wr >> 1);      // 64-unit row id (wave-uniform)
        const int tn = bn * 2 + wc;             // 64-unit col id (wave-uniform)
        const float wgt = (tn < tm) ? 0.0f : ((tn == tm) ? 1.0f : 2.0f);
        const bool hasPos = (tn == tm + 64);
        if (wgt != 0.0f) {
            const int rowBase = bm * 128 + wr * 32 + q * 4;
            const int colBase = bn * 128 + wc * 64 + m16;
            float nacc = 0.0f;
            #pragma unroll
            for (int j = 0; j < 4; ++j) {
                const int cg = colBase + j * 16;
                float p = 1.0f;
                #pragma unroll
                for (int i = 0; i < 2; ++i) {
                    const int rg0 = rowBase + i * 16;
                    #pragma unroll
                    for (int r = 0; r < 4; ++r) {
                        const float sv = acc[i][j][r];
                        float e = __expf(sv - LAM);
                        if (rg0 + r == cg) e = 0.0f;          // main diagonal
                        p *= (1.0f + e);
                        if (hasPos && cg == rg0 + r + N_ROWS) // positive pair
                            possum += log1pf(expf(-sv + LAM));
                    }
                }
                nacc += __logf(p);
            }
            negsum += nacc * wgt;
        }

        bm = nbm; bn = nbn; stA = nA; stB = nB;
    }

    // --- block reduction: one atomic per block ---
    #pragma unroll
    for (int off = 32; off; off >>= 1) {
        negsum += __shfl_xor(negsum, off);
        possum += __shfl_xor(possum, off);
    }
    const float part = negsum * (1.0f / (12.0f * (float)N_ROWS))
                     + possum * (1.0f / (float)N_ROWS);
    if (lane == 0) red[w] = part;
    __syncthreads();
    if (tid == 0) {
        float t = 0.0f;
        #pragma unroll
        for (int i = 0; i < 8; ++i) t += red[i];
        atomicAdd(out, t);
    }
    #undef ISSUE
}

extern "C" void kernel_launch(void* const* d_in, const int* in_sizes, int n_in,
                              void* d_out, int out_size, void* d_ws, size_t ws_size,
                              hipStream_t stream) {
    const float* ei = (const float*)d_in[0];
    const float* ej = (const float*)d_in[1];
    float* out = (float*)d_out;
    unsigned char* Z = (unsigned char*)d_ws;  // 8192*512 fp8 = 4 MB scratch

    normalize_kernel<<<2048, 256, 0, stream>>>(ei, ej, Z, out);
    simloss_kernel<<<GRID, 512, 0, stream>>>(Z, out);
}